// Round 3
// baseline (37.070 us; speedup 1.0000x reference)
//
#include <hip/hip_runtime.h>
#include <cmath>

// NCE LM loss. N = B*T rows, D = 1024, K = 20 noise ids, V = vocab.
// Fast path: 512 blocks x 256 thr (4 waves), 4 rows/block register-resident,
// noise chunks read from L1/L2 (no LDS staging, no pre-compute barrier),
// finalize fused via last-block pattern (counter zeroed by a 4B memset node).

#define RPB 4            // rows per block
#define KN  20           // noise count (fast path)

__device__ __forceinline__ float log_sigmoid_f(float x) {
    // stable log(sigmoid(x)) = min(x,0) - log1p(exp(-|x|))
    return fminf(x, 0.0f) - log1pf(expf(-fabsf(x)));
}

__device__ __forceinline__ float wave_reduce(float v) {
    #pragma unroll
    for (int off = 32; off > 0; off >>= 1) v += __shfl_xor(v, off, 64);
    return v;
}

__device__ __forceinline__ float fma4(float4 a, float4 b, float acc) {
    acc = fmaf(a.x, b.x, acc);
    acc = fmaf(a.y, b.y, acc);
    acc = fmaf(a.z, b.z, acc);
    return fmaf(a.w, b.w, acc);
}

__global__ __launch_bounds__(256) void nce_fused_kernel(
    const float* __restrict__ hidden,     // (N, 1024)
    const int*   __restrict__ targets,    // (N,)
    const float* __restrict__ W,          // (V, 1024)
    const int*   __restrict__ noise_ids,  // (20,)
    float* __restrict__ bpos,             // (nblocks,) per-block pos sums
    float* __restrict__ bneg,             // (nblocks,) per-block neg sums
    int*   __restrict__ counter,          // zeroed by memset node each call
    float* __restrict__ out,
    int N, float shift)
{
    __shared__ float sp[4], sn[4];
    __shared__ int   slast;

    const int tid  = threadIdx.x;
    const int wave = tid >> 6;
    const int lane = tid & 63;
    const int r0   = blockIdx.x * RPB;
    const int rowp = r0 + wave;
    const int nblocks = gridDim.x;

    // wave w owns noise ids [w*5, w*5+5)
    int nid[5];
    #pragma unroll
    for (int n = 0; n < 5; ++n) nid[n] = noise_ids[wave * 5 + n];

    // ---- 4 hidden rows into registers; lane owns elems {lane*4 + j*256} ----
    float4 h[RPB][4];
    #pragma unroll
    for (int r = 0; r < RPB; ++r)
        #pragma unroll
        for (int j = 0; j < 4; ++j)
            h[r][j] = *reinterpret_cast<const float4*>(
                hidden + (size_t)(r0 + r) * 1024 + lane * 4 + j * 256);

    // ---- pos dot: wave w handles row r0+w (hidden reload is L1-hot) ----
    const int tgt = targets[rowp];
    float pacc = 0.0f;
    #pragma unroll
    for (int j = 0; j < 4; ++j) {
        const float4 b = *reinterpret_cast<const float4*>(
            W + (size_t)tgt * 1024 + lane * 4 + j * 256);
        const float4 a = *reinterpret_cast<const float4*>(
            hidden + (size_t)rowp * 1024 + lane * 4 + j * 256);
        pacc = fma4(a, b, pacc);
    }

    // ---- neg dots: each noise chunk (16B) serves 4 register rows (64 FMA) ----
    float acc[5][RPB];
    #pragma unroll
    for (int n = 0; n < 5; ++n)
        #pragma unroll
        for (int r = 0; r < RPB; ++r) acc[n][r] = 0.0f;

    #pragma unroll
    for (int n = 0; n < 5; ++n) {
        float4 b[4];
        #pragma unroll
        for (int j = 0; j < 4; ++j)
            b[j] = *reinterpret_cast<const float4*>(
                W + (size_t)nid[n] * 1024 + lane * 4 + j * 256);
        #pragma unroll
        for (int j = 0; j < 4; ++j)
            #pragma unroll
            for (int r = 0; r < RPB; ++r)
                acc[n][r] = fma4(b[j], h[r][j], acc[n][r]);
    }

    // ---- reductions ----
    pacc = wave_reduce(pacc);
    #pragma unroll
    for (int n = 0; n < 5; ++n)
        #pragma unroll
        for (int r = 0; r < RPB; ++r)
            acc[n][r] = wave_reduce(acc[n][r]);

    if (lane == 0) {
        sp[wave] = log_sigmoid_f(pacc + shift);
        float ns = 0.0f;
        #pragma unroll
        for (int n = 0; n < 5; ++n)
            #pragma unroll
            for (int r = 0; r < RPB; ++r)
                ns += log_sigmoid_f(-(acc[n][r] + shift));
        sn[wave] = ns;
    }
    __syncthreads();
    if (tid == 0) {
        // device-scope release stores so the last block sees them cross-XCD
        __hip_atomic_store(&bpos[blockIdx.x], sp[0] + sp[1] + sp[2] + sp[3],
                           __ATOMIC_RELEASE, __HIP_MEMORY_SCOPE_AGENT);
        __hip_atomic_store(&bneg[blockIdx.x], sn[0] + sn[1] + sn[2] + sn[3],
                           __ATOMIC_RELEASE, __HIP_MEMORY_SCOPE_AGENT);
        slast = (__hip_atomic_fetch_add(counter, 1, __ATOMIC_ACQ_REL,
                                        __HIP_MEMORY_SCOPE_AGENT) == nblocks - 1);
    }
    __syncthreads();
    if (!slast) return;

    // ---- last arriving block: final deterministic tree over block partials ----
    float p = 0.0f, ng = 0.0f;
    for (int i = tid; i < nblocks; i += 256) {
        p  += __hip_atomic_load(&bpos[i], __ATOMIC_ACQUIRE, __HIP_MEMORY_SCOPE_AGENT);
        ng += __hip_atomic_load(&bneg[i], __ATOMIC_ACQUIRE, __HIP_MEMORY_SCOPE_AGENT);
    }
    p  = wave_reduce(p);
    ng = wave_reduce(ng);
    __syncthreads();   // reuse sp/sn safely
    if (lane == 0) { sp[wave] = p; sn[wave] = ng; }
    __syncthreads();
    if (tid == 0) {
        const float P  = sp[0] + sp[1] + sp[2] + sp[3];
        const float Ng = sn[0] + sn[1] + sn[2] + sn[3];
        out[0] = -P / (float)N - Ng / ((float)N * (float)KN);
    }
}

// ---- generic fallback (unexpected shapes): one block per row + finalize ----
__global__ __launch_bounds__(256) void nce_generic_kernel(
    const float* __restrict__ hidden, const int* __restrict__ targets,
    const float* __restrict__ W, const int* __restrict__ noise_ids,
    float* __restrict__ posp, float* __restrict__ negp,
    int D, int K, float shift)
{
    const int row  = blockIdx.x;
    const int tid  = threadIdx.x;
    const int wave = tid >> 6;
    const int lane = tid & 63;
    __shared__ float spos[4], sneg[4];

    const float* hrow = hidden + (size_t)row * D;
    const int tgt = targets[row];
    float pos = 0.0f, neg = 0.0f;
    for (int id = wave; id <= K; id += 4) {
        const int wrow = (id == 0) ? tgt : noise_ids[id - 1];
        const float* wv = W + (size_t)wrow * D;
        float acc = 0.0f;
        for (int k = lane; k < D; k += 64) acc = fmaf(hrow[k], wv[k], acc);
        acc = wave_reduce(acc);
        if (lane == 0) {
            const float s = acc + shift;
            if (id == 0) pos += log_sigmoid_f(s);
            else         neg += log_sigmoid_f(-s);
        }
    }
    if (lane == 0) { spos[wave] = pos; sneg[wave] = neg; }
    __syncthreads();
    if (tid == 0) {
        posp[row] = spos[0] + spos[1] + spos[2] + spos[3];
        negp[row] = sneg[0] + sneg[1] + sneg[2] + sneg[3];
    }
}

__global__ __launch_bounds__(256) void nce_finalize_kernel(
    const float* __restrict__ posp, const float* __restrict__ negp,
    float* __restrict__ out, int N, int K)
{
    __shared__ float sp[4], sn[4];
    const int tid  = threadIdx.x;
    const int wave = tid >> 6;
    const int lane = tid & 63;

    float p = 0.0f, n = 0.0f;
    for (int i = tid; i < N; i += 256) {
        p += posp[i];
        n += negp[i];
    }
    #pragma unroll
    for (int off = 32; off > 0; off >>= 1) {
        p += __shfl_xor(p, off, 64);
        n += __shfl_xor(n, off, 64);
    }
    if (lane == 0) { sp[wave] = p; sn[wave] = n; }
    __syncthreads();
    if (tid == 0) {
        const float P  = sp[0] + sp[1] + sp[2] + sp[3];
        const float Ng = sn[0] + sn[1] + sn[2] + sn[3];
        out[0] = -P / (float)N - Ng / ((float)N * (float)K);
    }
}

extern "C" void kernel_launch(void* const* d_in, const int* in_sizes, int n_in,
                              void* d_out, int out_size, void* d_ws, size_t ws_size,
                              hipStream_t stream) {
    const float* hidden    = (const float*)d_in[0];
    const int*   targets   = (const int*)d_in[1];
    const float* W         = (const float*)d_in[2];
    const int*   noise_ids = (const int*)d_in[3];

    const int N = in_sizes[1];             // B*T = 2048
    const int D = in_sizes[0] / N;         // 1024
    const int K = in_sizes[3];             // 20
    const int V = in_sizes[2] / D;         // 50257

    const float shift = logf((float)V) - logf((float)K);

    float* bpos = (float*)d_ws;            // nblocks (or N for fallback)
    float* bneg = bpos + N;                // nblocks (or N for fallback)
    int*   counter = (int*)(bneg + N);     // 4 bytes

    if (D == 1024 && K == KN && (N % RPB) == 0) {
        const int nblocks = N / RPB;
        hipMemsetAsync(counter, 0, sizeof(int), stream);
        nce_fused_kernel<<<nblocks, 256, 0, stream>>>(
            hidden, targets, W, noise_ids, bpos, bneg, counter,
            (float*)d_out, N, shift);
    } else {
        nce_generic_kernel<<<N, 256, 0, stream>>>(
            hidden, targets, W, noise_ids, bpos, bneg, D, K, shift);
        nce_finalize_kernel<<<1, 256, 0, stream>>>(bpos, bneg, (float*)d_out, N, K);
    }
}

// Round 4
// 22.348 us; speedup vs baseline: 1.6588x; 1.6588x over previous
//
#include <hip/hip_runtime.h>
#include <cmath>

// NCE LM loss. N = B*T rows, D = 1024, K = 20 noise ids, V = vocab.
// R4: R1's high-TLP geometry (2048 blocks x 256 thr, one row per block),
// minus its serial overhead: hidden chunk register-resident (no LDS stage,
// no pre-compute barrier), all dot partials accumulated first, butterflies
// batched/interleaved at the end. Two kernels (rows + tiny finalize).

#define KN 20            // noise count (fast path)

__device__ __forceinline__ float log_sigmoid_f(float x) {
    // stable log(sigmoid(x)) = min(x,0) - log1p(exp(-|x|))
    return fminf(x, 0.0f) - log1pf(expf(-fabsf(x)));
}

__device__ __forceinline__ float fma4(float4 a, float4 b, float acc) {
    acc = fmaf(a.x, b.x, acc);
    acc = fmaf(a.y, b.y, acc);
    acc = fmaf(a.z, b.z, acc);
    return fmaf(a.w, b.w, acc);
}

__device__ __forceinline__ float wave_reduce(float v) {
    #pragma unroll
    for (int off = 32; off > 0; off >>= 1) v += __shfl_xor(v, off, 64);
    return v;
}

// One row per block. Wave w owns ids {w, w+4, w+8, ...} <= 20 (id 0 = target).
__global__ __launch_bounds__(256) void nce_rows_kernel(
    const float* __restrict__ hidden,     // (N, 1024)
    const int*   __restrict__ targets,    // (N,)
    const float* __restrict__ W,          // (V, 1024)
    const int*   __restrict__ noise_ids,  // (20,)
    float* __restrict__ posp,             // (N,)
    float* __restrict__ negp,             // (N,)
    float shift)
{
    __shared__ float sp[4], sn[4];

    const int row  = blockIdx.x;
    const int tid  = threadIdx.x;
    const int wave = tid >> 6;
    const int lane = tid & 63;

    // Hidden row chunk in registers: lane owns elems {lane*4 + j*256}.
    // Each of the 4 loads is a contiguous 1KB wave transaction.
    const float* hrow = hidden + (size_t)row * 1024;
    float4 h[4];
    #pragma unroll
    for (int j = 0; j < 4; ++j)
        h[j] = *reinterpret_cast<const float4*>(hrow + lane * 4 + j * 256);

    const int tgt = targets[row];

    // Phase 1: lane-local partials for up to 6 dots (independent accumulators,
    // statically indexed; loads across slots overlap FMAs).
    float acc[6];
    #pragma unroll
    for (int s = 0; s < 6; ++s) {
        const int id = wave + 4 * s;
        float a = 0.0f;
        if (id <= KN) {
            const int wrow = (id == 0) ? tgt : noise_ids[id - 1];
            const float* wr = W + (size_t)wrow * 1024;
            #pragma unroll
            for (int j = 0; j < 4; ++j) {
                const float4 b = *reinterpret_cast<const float4*>(wr + lane * 4 + j * 256);
                a = fma4(h[j], b, a);
            }
        }
        acc[s] = a;
    }

    // Phase 2: 6 butterflies, round-major so the 6 independent chains pipeline.
    #pragma unroll
    for (int off = 32; off > 0; off >>= 1)
        #pragma unroll
        for (int s = 0; s < 6; ++s)
            acc[s] += __shfl_xor(acc[s], off, 64);

    // Phase 3: log-sigmoid terms on lane 0, one barrier, block write.
    if (lane == 0) {
        float pos = 0.0f, neg = 0.0f;
        #pragma unroll
        for (int s = 0; s < 6; ++s) {
            const int id = wave + 4 * s;
            if (id > KN) continue;
            const float sc = acc[s] + shift;
            if (id == 0) pos = log_sigmoid_f(sc);
            else         neg += log_sigmoid_f(-sc);
        }
        sp[wave] = pos;
        sn[wave] = neg;
    }
    __syncthreads();
    if (tid == 0) {
        posp[row] = sp[0] + sp[1] + sp[2] + sp[3];
        negp[row] = sn[0] + sn[1] + sn[2] + sn[3];
    }
}

// ---- generic fallback for unexpected shapes: one block per row ----
__global__ __launch_bounds__(256) void nce_generic_kernel(
    const float* __restrict__ hidden, const int* __restrict__ targets,
    const float* __restrict__ W, const int* __restrict__ noise_ids,
    float* __restrict__ posp, float* __restrict__ negp,
    int D, int K, float shift)
{
    const int row  = blockIdx.x;
    const int tid  = threadIdx.x;
    const int wave = tid >> 6;
    const int lane = tid & 63;
    __shared__ float spos[4], sneg[4];

    const float* hrow = hidden + (size_t)row * D;
    const int tgt = targets[row];
    float pos = 0.0f, neg = 0.0f;
    for (int id = wave; id <= K; id += 4) {
        const int wrow = (id == 0) ? tgt : noise_ids[id - 1];
        const float* wv = W + (size_t)wrow * D;
        float acc = 0.0f;
        for (int k = lane; k < D; k += 64) acc = fmaf(hrow[k], wv[k], acc);
        acc = wave_reduce(acc);
        if (lane == 0) {
            const float s = acc + shift;
            if (id == 0) pos += log_sigmoid_f(s);
            else         neg += log_sigmoid_f(-s);
        }
    }
    if (lane == 0) { spos[wave] = pos; sneg[wave] = neg; }
    __syncthreads();
    if (tid == 0) {
        posp[row] = spos[0] + spos[1] + spos[2] + spos[3];
        negp[row] = sneg[0] + sneg[1] + sneg[2] + sneg[3];
    }
}

__global__ __launch_bounds__(256) void nce_finalize_kernel(
    const float* __restrict__ posp, const float* __restrict__ negp,
    float* __restrict__ out, int N, int K)
{
    __shared__ float sp[4], sn[4];
    const int tid  = threadIdx.x;
    const int wave = tid >> 6;
    const int lane = tid & 63;

    float p = 0.0f, n = 0.0f;
    for (int i = tid; i < N; i += 256) {
        p += posp[i];
        n += negp[i];
    }
    #pragma unroll
    for (int off = 32; off > 0; off >>= 1) {
        p += __shfl_xor(p, off, 64);
        n += __shfl_xor(n, off, 64);
    }
    if (lane == 0) { sp[wave] = p; sn[wave] = n; }
    __syncthreads();
    if (tid == 0) {
        const float P  = sp[0] + sp[1] + sp[2] + sp[3];
        const float Ng = sn[0] + sn[1] + sn[2] + sn[3];
        out[0] = -P / (float)N - Ng / ((float)N * (float)K);
    }
}

extern "C" void kernel_launch(void* const* d_in, const int* in_sizes, int n_in,
                              void* d_out, int out_size, void* d_ws, size_t ws_size,
                              hipStream_t stream) {
    const float* hidden    = (const float*)d_in[0];
    const int*   targets   = (const int*)d_in[1];
    const float* W         = (const float*)d_in[2];
    const int*   noise_ids = (const int*)d_in[3];

    const int N = in_sizes[1];             // B*T = 2048
    const int D = in_sizes[0] / N;         // 1024
    const int K = in_sizes[3];             // 20
    const int V = in_sizes[2] / D;         // 50257

    const float shift = logf((float)V) - logf((float)K);

    float* posp = (float*)d_ws;            // N floats
    float* negp = posp + N;                // N floats

    if (D == 1024 && K == KN) {
        nce_rows_kernel<<<N, 256, 0, stream>>>(
            hidden, targets, W, noise_ids, posp, negp, shift);
    } else {
        nce_generic_kernel<<<N, 256, 0, stream>>>(
            hidden, targets, W, noise_ids, posp, negp, D, K, shift);
    }
    nce_finalize_kernel<<<1, 256, 0, stream>>>(posp, negp, (float*)d_out, N, K);
}

// Round 5
// 17.350 us; speedup vs baseline: 2.1365x; 1.2880x over previous
//
#include <hip/hip_runtime.h>
#include <cmath>

// NCE LM loss. N = B*T rows, D = 1024, K = 20 noise ids, V = vocab.
// R5: R1/R4 geometry (2048 blocks x 256 thr, one row/block) with minimal
// per-block work: register-resident hidden chunk, batched butterflies,
// log-sigmoid parallelized across lanes 0..5, normalization folded so each
// block writes ONE float contribution; finalize is a pure 2048-float sum.

#define KN 20            // noise count (fast path)

__device__ __forceinline__ float log_sigmoid_f(float x) {
    // stable log(sigmoid(x)) = min(x,0) - log1p(exp(-|x|))
    return fminf(x, 0.0f) - log1pf(expf(-fabsf(x)));
}

__device__ __forceinline__ float fma4(float4 a, float4 b, float acc) {
    acc = fmaf(a.x, b.x, acc);
    acc = fmaf(a.y, b.y, acc);
    acc = fmaf(a.z, b.z, acc);
    return fmaf(a.w, b.w, acc);
}

__device__ __forceinline__ float wave_reduce(float v) {
    #pragma unroll
    for (int off = 32; off > 0; off >>= 1) v += __shfl_xor(v, off, 64);
    return v;
}

// One row per block. Wave w owns ids {w, w+4, ...} <= 20 (id 0 = target row).
__global__ __launch_bounds__(256) void nce_rows_kernel(
    const float* __restrict__ hidden,     // (N, 1024)
    const int*   __restrict__ targets,    // (N,)
    const float* __restrict__ W,          // (V, 1024)
    const int*   __restrict__ noise_ids,  // (20,)
    float* __restrict__ cb,               // (N,) per-block loss contributions
    float inv_n, float inv_nk, float shift)
{
    __shared__ float sc4[4];

    const int row  = blockIdx.x;
    const int tid  = threadIdx.x;
    const int wave = tid >> 6;
    const int lane = tid & 63;

    // Hidden row chunk in registers: lane owns elems {lane*4 + j*256}.
    const float* hrow = hidden + (size_t)row * 1024;
    float4 h[4];
    #pragma unroll
    for (int j = 0; j < 4; ++j)
        h[j] = *reinterpret_cast<const float4*>(hrow + lane * 4 + j * 256);

    const int tgt = targets[row];

    // Phase 1: lane-local partials for up to 6 dots (static accumulators).
    float acc[6];
    #pragma unroll
    for (int s = 0; s < 6; ++s) {
        const int id = wave + 4 * s;
        float a = 0.0f;
        if (id <= KN) {
            const int wrow = (id == 0) ? tgt : noise_ids[id - 1];
            const float* wr = W + (size_t)wrow * 1024;
            #pragma unroll
            for (int j = 0; j < 4; ++j) {
                const float4 b = *reinterpret_cast<const float4*>(wr + lane * 4 + j * 256);
                a = fma4(h[j], b, a);
            }
        }
        acc[s] = a;
    }

    // Phase 2: 6 butterflies, round-major so independent chains pipeline.
    // Afterwards every lane holds all 6 full sums.
    #pragma unroll
    for (int off = 32; off > 0; off >>= 1)
        #pragma unroll
        for (int s = 0; s < 6; ++s)
            acc[s] += __shfl_xor(acc[s], off, 64);

    // Phase 3: lanes 0..5 each evaluate one log-sigmoid term in parallel
    // (cndmask select, no dynamic indexing), normalization folded in.
    float v = acc[0];
    v = (lane == 1) ? acc[1] : v;
    v = (lane == 2) ? acc[2] : v;
    v = (lane == 3) ? acc[3] : v;
    v = (lane == 4) ? acc[4] : v;
    v = (lane == 5) ? acc[5] : v;
    const int id = wave + 4 * lane;
    float term = 0.0f;
    if (lane < 6 && id <= KN) {
        const float sc = v + shift;
        term = (id == 0) ? (-log_sigmoid_f(sc)) * inv_n
                         : (-log_sigmoid_f(-sc)) * inv_nk;
    }
    // Sum lanes 0..7 (lanes 6,7 contribute zero).
    term += __shfl_xor(term, 1, 64);
    term += __shfl_xor(term, 2, 64);
    term += __shfl_xor(term, 4, 64);

    if (lane == 0) sc4[wave] = term;
    __syncthreads();
    if (tid == 0) cb[row] = sc4[0] + sc4[1] + sc4[2] + sc4[3];
}

// ---- generic fallback for unexpected shapes: one block per row ----
__global__ __launch_bounds__(256) void nce_generic_kernel(
    const float* __restrict__ hidden, const int* __restrict__ targets,
    const float* __restrict__ W, const int* __restrict__ noise_ids,
    float* __restrict__ cb, int D, int K, float inv_n, float inv_nk, float shift)
{
    const int row  = blockIdx.x;
    const int tid  = threadIdx.x;
    const int wave = tid >> 6;
    const int lane = tid & 63;
    __shared__ float sc4[4];

    const float* hrow = hidden + (size_t)row * D;
    const int tgt = targets[row];
    float c = 0.0f;
    for (int id = wave; id <= K; id += 4) {
        const int wrow = (id == 0) ? tgt : noise_ids[id - 1];
        const float* wv = W + (size_t)wrow * D;
        float acc = 0.0f;
        for (int k = lane; k < D; k += 64) acc = fmaf(hrow[k], wv[k], acc);
        acc = wave_reduce(acc);
        if (lane == 0) {
            const float s = acc + shift;
            c += (id == 0) ? (-log_sigmoid_f(s)) * inv_n
                           : (-log_sigmoid_f(-s)) * inv_nk;
        }
    }
    if (lane == 0) sc4[wave] = c;
    __syncthreads();
    if (tid == 0) cb[row] = sc4[0] + sc4[1] + sc4[2] + sc4[3];
}

// Pure deterministic sum of per-block contributions.
__global__ __launch_bounds__(256) void nce_sum_kernel(
    const float* __restrict__ cb, float* __restrict__ out, int n)
{
    __shared__ float sp[4];
    const int tid  = threadIdx.x;
    const int wave = tid >> 6;
    const int lane = tid & 63;

    float p = 0.0f;
    for (int i = tid; i < n; i += 256) p += cb[i];
    p = wave_reduce(p);
    if (lane == 0) sp[wave] = p;
    __syncthreads();
    if (tid == 0) out[0] = sp[0] + sp[1] + sp[2] + sp[3];
}

extern "C" void kernel_launch(void* const* d_in, const int* in_sizes, int n_in,
                              void* d_out, int out_size, void* d_ws, size_t ws_size,
                              hipStream_t stream) {
    const float* hidden    = (const float*)d_in[0];
    const int*   targets   = (const int*)d_in[1];
    const float* W         = (const float*)d_in[2];
    const int*   noise_ids = (const int*)d_in[3];

    const int N = in_sizes[1];             // B*T = 2048
    const int D = in_sizes[0] / N;         // 1024
    const int K = in_sizes[3];             // 20
    const int V = in_sizes[2] / D;         // 50257

    const float shift  = logf((float)V) - logf((float)K);
    const float inv_n  = 1.0f / (float)N;
    const float inv_nk = 1.0f / ((float)N * (float)K);

    float* cb = (float*)d_ws;              // N floats, all overwritten each call

    if (D == 1024 && K == KN) {
        nce_rows_kernel<<<N, 256, 0, stream>>>(
            hidden, targets, W, noise_ids, cb, inv_n, inv_nk, shift);
    } else {
        nce_generic_kernel<<<N, 256, 0, stream>>>(
            hidden, targets, W, noise_ids, cb, D, K, inv_n, inv_nk, shift);
    }
    nce_sum_kernel<<<1, 256, 0, stream>>>(cb, (float*)d_out, N);
}